// Round 1
// baseline (2404.602 us; speedup 1.0000x reference)
//
#include <hip/hip_runtime.h>
#include <hip/hip_bf16.h>

// Problem constants
#define B_    16
#define H_    768
#define W_    768
#define HW_   (H_*W_)        // 589824
#define P_    64
#define NP_   4
#define TOPK_ 100
#define NPATCH (B_*NP_)      // 64 patches

// ---------------------------------------------------------------------------
// flag = any(source < 0)
// ---------------------------------------------------------------------------
__global__ void k_zero_flag(int* flag){ if (threadIdx.x==0) *flag = 0; }

__global__ void k_flag(const float4* __restrict__ s, int n4, int* __restrict__ flag){
  int idx = blockIdx.x*blockDim.x + threadIdx.x;
  int strd = gridDim.x*blockDim.x;
  bool neg = false;
  for (int i=idx; i<n4; i+=strd){
    float4 q = s[i];
    neg = neg || (q.x<0.f) || (q.y<0.f) || (q.z<0.f) || (q.w<0.f);
  }
  if (__any((int)neg)){
    if ((threadIdx.x & 63) == 0) atomicOr(flag, 1);
  }
}

// ---------------------------------------------------------------------------
// detector: mask = sigmoid(20*(brightness-0.65)) * sigmoid(20*(0.15-sat))
// ---------------------------------------------------------------------------
__global__ void k_detector(const float* __restrict__ src, const int* __restrict__ flag,
                           float* __restrict__ mask){
  int i = blockIdx.x*blockDim.x + threadIdx.x;
  if (i >= B_*HW_) return;
  int b = i / HW_;
  int p = i - b*HW_;
  const float* sb = src + (size_t)b*3*HW_;
  float r = sb[p], g = sb[HW_+p], bl = sb[2*HW_+p];
  if (*flag){ r = (r+1.f)*0.5f; g = (g+1.f)*0.5f; bl = (bl+1.f)*0.5f; }
  float br = 0.299f*r + 0.587f*g + 0.114f*bl;
  float bm = 1.f/(1.f + expf(-20.f*(br - 0.65f)));
  float mx = fmaxf(r, fmaxf(g, bl));
  float mn = fminf(r, fminf(g, bl));
  float ls = 1.f/(1.f + expf(-20.f*(0.15f - (mx-mn))));
  mask[i] = bm*ls;
}

// ---------------------------------------------------------------------------
// separable 15x15 box filter (zero pad, divide by 225 at the end)
// ---------------------------------------------------------------------------
__global__ void k_box_row(const float* __restrict__ in, float* __restrict__ out){
  int i = blockIdx.x*blockDim.x + threadIdx.x;
  if (i >= B_*HW_) return;
  int x = i % W_;
  int base = i - x;
  float s = 0.f;
  #pragma unroll
  for (int d=-7; d<=7; ++d){
    int xx = x + d;
    if (xx >= 0 && xx < W_) s += in[base + xx];
  }
  out[i] = s;
}

__global__ void k_box_col(const float* __restrict__ in, float* __restrict__ out){
  int i = blockIdx.x*blockDim.x + threadIdx.x;
  if (i >= B_*HW_) return;
  int p = i % HW_;
  int y = p / W_;
  float s = 0.f;
  #pragma unroll
  for (int d=-7; d<=7; ++d){
    int yy = y + d;
    if (yy >= 0 && yy < H_) s += in[i + d*W_];
  }
  out[i] = s / 225.0f;
}

// ---------------------------------------------------------------------------
// per-image exact top-100 (value desc, index asc on ties) -> 4 patch coords
// two-level 8192-bin histogram radix select, then ordered selection in LDS
// ---------------------------------------------------------------------------
__global__ __launch_bounds__(1024) void k_topk(const float* __restrict__ win,
                                               const int* __restrict__ rand_sel,
                                               int* __restrict__ coords){
  const int b = blockIdx.x;
  const float* v = win + (size_t)b*HW_;
  __shared__ unsigned hist[8192];
  __shared__ unsigned chunk[1024];
  __shared__ float    cval[1024];
  __shared__ unsigned cidx[1024];
  __shared__ unsigned s_top[TOPK_];
  __shared__ unsigned s_cnt;
  __shared__ int s_t1, s_ab1, s_t2;
  __shared__ float    s_rv[16];
  __shared__ unsigned s_ri[16];
  __shared__ unsigned s_win;
  const int t = threadIdx.x;

  // phase 1: coarse histogram (values are in [0,1))
  for (int i=t;i<8192;i+=1024) hist[i]=0u;
  __syncthreads();
  for (int i=t;i<HW_;i+=1024){
    float x = v[i];
    int bin = (int)(x*8192.0f);
    bin = bin<0?0:(bin>8191?8191:bin);
    atomicAdd(&hist[bin], 1u);
  }
  __syncthreads();
  unsigned cs = 0;
  #pragma unroll
  for (int j=0;j<8;j++) cs += hist[t*8+j];
  chunk[t] = cs;
  __syncthreads();
  if (t==0){
    unsigned acc = 0; int tc = 1023;
    for (; tc>0; --tc){ if (acc + chunk[tc] >= (unsigned)TOPK_) break; acc += chunk[tc]; }
    int bb = tc*8+7;
    for (; bb>tc*8; --bb){ if (acc + hist[bb] >= (unsigned)TOPK_) break; acc += hist[bb]; }
    s_t1 = bb; s_ab1 = (int)acc;
  }
  __syncthreads();
  const int t1 = s_t1;
  const int ab1 = s_ab1;
  const float lo = (float)t1 * (1.0f/8192.0f);

  // phase 2: refine inside bin t1 (sub-bin width 1/2^26 -> ~unique fp32 values)
  for (int i=t;i<8192;i+=1024) hist[i]=0u;
  __syncthreads();
  for (int i=t;i<HW_;i+=1024){
    float x = v[i];
    int bin = (int)(x*8192.0f); bin = bin<0?0:(bin>8191?8191:bin);
    if (bin==t1){
      int sb = (int)((x-lo)*67108864.0f); sb = sb<0?0:(sb>8191?8191:sb);
      atomicAdd(&hist[sb], 1u);
    }
  }
  __syncthreads();
  cs = 0;
  #pragma unroll
  for (int j=0;j<8;j++) cs += hist[t*8+j];
  chunk[t] = cs;
  __syncthreads();
  if (t==0){
    unsigned acc = (unsigned)ab1; int tc = 1023;
    for (; tc>0; --tc){ if (acc + chunk[tc] >= (unsigned)TOPK_) break; acc += chunk[tc]; }
    int bb = tc*8+7;
    for (; bb>tc*8; --bb){ if (acc + hist[bb] >= (unsigned)TOPK_) break; acc += hist[bb]; }
    s_t2 = bb; s_cnt = 0u;
  }
  __syncthreads();
  const int t2 = s_t2;

  // phase 3: collect candidates above threshold (count in [100, 100+ties))
  for (int i=t;i<HW_;i+=1024){
    float x = v[i];
    int bin = (int)(x*8192.0f); bin = bin<0?0:(bin>8191?8191:bin);
    bool take = (bin > t1);
    if (!take && bin==t1){
      int sb = (int)((x-lo)*67108864.0f); sb = sb<0?0:(sb>8191?8191:sb);
      take = (sb >= t2);
    }
    if (take){
      unsigned u = atomicAdd(&s_cnt, 1u);
      if (u < 1024u){ cval[u] = x; cidx[u] = (unsigned)i; }
    }
  }
  __syncthreads();
  const unsigned M = s_cnt < 1024u ? s_cnt : 1024u;

  // phase 4: ordered selection of first 100 (value desc, idx asc)
  float    mv = (t < (int)M) ? cval[t] : -1.0f;
  unsigned mi = (t < (int)M) ? cidx[t] : 0xFFFFFFFFu;
  for (int r=0; r<TOPK_; ++r){
    float bv = mv; unsigned bi = mi;
    #pragma unroll
    for (int o=32;o>=1;o>>=1){
      float    ov = __shfl_xor(bv, o);
      unsigned oi = __shfl_xor(bi, o);
      if (ov > bv || (ov == bv && oi < bi)){ bv = ov; bi = oi; }
    }
    if ((t & 63) == 0){ s_rv[t>>6] = bv; s_ri[t>>6] = bi; }
    __syncthreads();
    if (t < 64){
      float    bv2 = (t < 16) ? s_rv[t] : -1.0f;
      unsigned bi2 = (t < 16) ? s_ri[t] : 0xFFFFFFFFu;
      #pragma unroll
      for (int o=8;o>=1;o>>=1){
        float    ov = __shfl_xor(bv2, o);
        unsigned oi = __shfl_xor(bi2, o);
        if (ov > bv2 || (ov == bv2 && oi < bi2)){ bv2 = ov; bi2 = oi; }
      }
      if (t==0){ s_top[r] = bi2; s_win = bi2; }
    }
    __syncthreads();
    if (mi == s_win){ mv = -1.0f; mi = 0xFFFFFFFFu; }
    __syncthreads();
  }

  // coords for the 4 selected patches
  if (t < NP_){
    int rs = rand_sel[b*NP_ + t];
    rs = rs<0?0:(rs>99?99:rs);
    unsigned sel = s_top[rs];
    int rr = (int)(sel / (unsigned)W_);
    int cc = (int)(sel % (unsigned)W_);
    int y = rr - P_/2; y = y<0?0:(y>(H_-P_)?(H_-P_):y);
    int x = cc - P_/2; x = x<0?0:(x>(W_-P_)?(W_-P_):x);
    coords[(b*NP_+t)*2]   = y;
    coords[(b*NP_+t)*2+1] = x;
  }
}

// ---------------------------------------------------------------------------
// gather 64 patches of (3,64,64) from pred
// ---------------------------------------------------------------------------
__global__ void k_patch(const float* __restrict__ pred, const int* __restrict__ coords,
                        float* __restrict__ patches){
  int i = blockIdx.x*blockDim.x + threadIdx.x;
  if (i >= NPATCH*3*P_*P_) return;
  int x  = i & 63;
  int y  = (i >> 6) & 63;
  int c  = (i >> 12) % 3;
  int bp = i / (3*P_*P_);
  int b  = bp >> 2;
  int py = coords[bp*2], px = coords[bp*2+1];
  patches[i] = pred[(((size_t)b*3 + c)*H_ + (py+y))*W_ + (px+x)];
}

// ---------------------------------------------------------------------------
// conv1: 3->64, 64x64 -> 32x32, k4 s2 p1, + bias + leaky_relu(0.2) at store
// one thread per (n, co, oy), computes a full 32-wide output row
// ---------------------------------------------------------------------------
__global__ __launch_bounds__(256) void k_conv1(const float* __restrict__ in,
    const float* __restrict__ w, const float* __restrict__ bias, float* __restrict__ out){
  int id = blockIdx.x*256 + threadIdx.x;
  if (id >= NPATCH*64*32) return;
  const int oy = id % 32;
  const int co = (id/32) % 64;
  const int n  = id / (32*64);
  float acc[32];
  #pragma unroll
  for (int o=0;o<32;o++) acc[o]=0.f;
  const float* inN = in + (size_t)n*3*64*64;
  #pragma unroll
  for (int ci=0;ci<3;ci++){
    #pragma unroll
    for (int ky=0;ky<4;ky++){
      const int iy = oy*2 - 1 + ky;
      if (iy < 0 || iy >= 64) continue;
      float raw[64];
      const float4* rp = reinterpret_cast<const float4*>(inN + ci*4096 + iy*64);
      #pragma unroll
      for (int j=0;j<16;j++){ float4 q=rp[j]; raw[4*j]=q.x; raw[4*j+1]=q.y; raw[4*j+2]=q.z; raw[4*j+3]=q.w; }
      const float4 wq = *reinterpret_cast<const float4*>(w + ((co*3+ci)*4+ky)*4);
      const float wk[4] = {wq.x, wq.y, wq.z, wq.w};
      #pragma unroll
      for (int kx=0;kx<4;kx++){
        #pragma unroll
        for (int ox=0;ox<32;ox++){
          const int ix = ox*2 - 1 + kx;
          if (ix >= 0 && ix < 64) acc[ox] += raw[ix]*wk[kx];
        }
      }
    }
  }
  const float bv = bias[co];
  #pragma unroll
  for (int ox=0;ox<32;ox++){
    float u = acc[ox] + bv;
    out[(((size_t)n*64 + co)*32 + oy)*32 + ox] = u > 0.f ? u : 0.2f*u;
  }
}

// ---------------------------------------------------------------------------
// generic s2/p1 k4 conv for layers 2..4. Optionally applies BN(scale,shift)+lrelu
// to the INPUT (so z tensors are stored raw). One thread = (n, co-pair, oy).
// ---------------------------------------------------------------------------
template<int CI, int CO, int HI, bool BN_IN>
__global__ __launch_bounds__(256) void k_conv_s2(const float* __restrict__ in,
    const float* __restrict__ w, const float* __restrict__ bias,
    const float* __restrict__ scale, const float* __restrict__ shift,
    float* __restrict__ out){
  constexpr int HO = HI/2, WI = HI, WO = HI/2, NCOG = CO/2;
  int id = blockIdx.x*256 + threadIdx.x;
  if (id >= NPATCH*NCOG*HO) return;
  const int oy  = id % HO;
  const int cog = (id/HO) % NCOG;
  const int n   = id / (HO*NCOG);
  const int co0 = cog*2;
  float acc[2][WO];
  #pragma unroll
  for (int a=0;a<2;a++){
    #pragma unroll
    for (int o=0;o<WO;o++) acc[a][o]=0.f;
  }
  const float* inN = in + (size_t)n*CI*HI*WI;
  for (int ci=0; ci<CI; ++ci){
    float sc = 1.f, sh = 0.f;
    if constexpr (BN_IN){ sc = scale[ci]; sh = shift[ci]; }
    const float* inC = inN + ci*HI*WI;
    #pragma unroll
    for (int ky=0;ky<4;ky++){
      const int iy = oy*2 - 1 + ky;
      if (iy < 0 || iy >= HI) continue;
      float raw[WI];
      const float4* rp = reinterpret_cast<const float4*>(inC + iy*WI);
      #pragma unroll
      for (int j=0;j<WI/4;j++){ float4 q=rp[j]; raw[4*j]=q.x; raw[4*j+1]=q.y; raw[4*j+2]=q.z; raw[4*j+3]=q.w; }
      if constexpr (BN_IN){
        #pragma unroll
        for (int j=0;j<WI;j++){ float x = raw[j]*sc + sh; raw[j] = x > 0.f ? x : 0.2f*x; }
      }
      #pragma unroll
      for (int c2=0;c2<2;c2++){
        const float4 wq = *reinterpret_cast<const float4*>(w + (((size_t)(co0+c2)*CI + ci)*4 + ky)*4);
        const float wk[4] = {wq.x, wq.y, wq.z, wq.w};
        #pragma unroll
        for (int kx=0;kx<4;kx++){
          #pragma unroll
          for (int ox=0;ox<WO;ox++){
            const int ix = ox*2 - 1 + kx;
            if (ix >= 0 && ix < WI) acc[c2][ox] += raw[ix]*wk[kx];
          }
        }
      }
    }
  }
  #pragma unroll
  for (int c2=0;c2<2;c2++){
    const float bv = bias[co0+c2];
    #pragma unroll
    for (int ox=0;ox<WO;ox++){
      out[(((size_t)n*CO + co0+c2)*HO + oy)*WO + ox] = acc[c2][ox] + bv;
    }
  }
}

// ---------------------------------------------------------------------------
// training-mode BN statistics -> per-channel scale/shift
// scale = g*rsqrt(var+eps); shift = be - mean*scale   (biased var)
// ---------------------------------------------------------------------------
template<int CO, int PX>
__global__ __launch_bounds__(256) void k_bnstats(const float* __restrict__ z,
    const float* __restrict__ g, const float* __restrict__ be,
    float* __restrict__ scale, float* __restrict__ shift){
  const int c = blockIdx.x, t = threadIdx.x;
  double s = 0.0, q = 0.0;
  for (int i=t; i<NPATCH*PX; i+=256){
    const int n = i / PX, p = i % PX;
    const float x = z[((size_t)n*CO + c)*PX + p];
    s += (double)x; q += (double)x*(double)x;
  }
  #pragma unroll
  for (int o=32;o>=1;o>>=1){ s += __shfl_down(s,o); q += __shfl_down(q,o); }
  __shared__ double ls[4], lq[4];
  if ((t & 63) == 0){ ls[t>>6] = s; lq[t>>6] = q; }
  __syncthreads();
  if (t==0){
    const double S = ls[0]+ls[1]+ls[2]+ls[3];
    const double Q = lq[0]+lq[1]+lq[2]+lq[3];
    const double cnt = (double)(NPATCH*PX);
    const double m  = S/cnt;
    const double var = Q/cnt - m*m;
    const float scl = g[c] / sqrtf((float)var + 1e-5f);
    scale[c] = scl;
    shift[c] = be[c] - (float)m*scl;
  }
}

// ---------------------------------------------------------------------------
// conv5: 512 -> 1, 4x4 input, k4 s1 p0 (a dot product), BN4+lrelu on input
// ---------------------------------------------------------------------------
__global__ __launch_bounds__(256) void k_conv5(const float* __restrict__ z4,
    const float* __restrict__ scale, const float* __restrict__ shift,
    const float* __restrict__ w5, const float* __restrict__ b5,
    float* __restrict__ logits){
  const int n = blockIdx.x, t = threadIdx.x;
  float part = 0.f;
  for (int k=t; k<8192; k+=256){
    const int ci = k >> 4, px = k & 15;
    float x = z4[((size_t)n*512 + ci)*16 + px];
    x = x*scale[ci] + shift[ci];
    x = x > 0.f ? x : 0.2f*x;
    part += x * w5[k];
  }
  #pragma unroll
  for (int o=32;o>=1;o>>=1) part += __shfl_down(part, o);
  __shared__ float ls[4];
  if ((t & 63) == 0) ls[t>>6] = part;
  __syncthreads();
  if (t==0) logits[n] = ls[0]+ls[1]+ls[2]+ls[3] + b5[0];
}

// ---------------------------------------------------------------------------
// loss = mean(softplus(-logit)) over 64 patches
// ---------------------------------------------------------------------------
__global__ void k_loss(const float* __restrict__ logits, float* __restrict__ out){
  const int t = threadIdx.x;
  float u  = -logits[t];
  float sp = fmaxf(u, 0.f) + log1pf(expf(-fabsf(u)));
  #pragma unroll
  for (int o=32;o>=1;o>>=1) sp += __shfl_down(sp, o);
  if (t==0) out[0] = sp * (1.0f/64.0f);
}

// ---------------------------------------------------------------------------
extern "C" void kernel_launch(void* const* d_in, const int* in_sizes, int n_in,
                              void* d_out, int out_size, void* d_ws, size_t ws_size,
                              hipStream_t stream) {
  const float* pred     = (const float*)d_in[0];
  const float* source   = (const float*)d_in[1];
  const int*   rand_sel = (const int*)  d_in[2];
  const float* w1 = (const float*)d_in[3];  const float* b1 = (const float*)d_in[4];
  const float* w2 = (const float*)d_in[5];  const float* b2 = (const float*)d_in[6];
  const float* g2 = (const float*)d_in[7];  const float* be2= (const float*)d_in[8];
  const float* w3 = (const float*)d_in[9];  const float* b3 = (const float*)d_in[10];
  const float* g3 = (const float*)d_in[11]; const float* be3= (const float*)d_in[12];
  const float* w4 = (const float*)d_in[13]; const float* b4 = (const float*)d_in[14];
  const float* g4 = (const float*)d_in[15]; const float* be4= (const float*)d_in[16];
  const float* w5 = (const float*)d_in[17]; const float* b5 = (const float*)d_in[18];

  // workspace layout (floats); total ~27.6M floats ~= 110 MB
  float* ws = (float*)d_ws;
  size_t o = 0;
  int*   flag    = (int*)(ws + o);      o += 16;
  float* maskbuf = ws + o;              o += (size_t)B_*HW_;   // mask, later window
  float* rowsum  = ws + o;              o += (size_t)B_*HW_;
  int*   coords  = (int*)(ws + o);      o += 128;
  float* patches = ws + o;              o += (size_t)NPATCH*3*64*64;
  float* a1      = ws + o;              o += (size_t)NPATCH*64*32*32;
  float* z2      = ws + o;              o += (size_t)NPATCH*128*16*16;
  float* z3      = ws + o;              o += (size_t)NPATCH*256*8*8;
  float* z4      = ws + o;              o += (size_t)NPATCH*512*4*4;
  float* scale2  = ws + o;              o += 128;
  float* shift2  = ws + o;              o += 128;
  float* scale3  = ws + o;              o += 256;
  float* shift3  = ws + o;              o += 256;
  float* scale4  = ws + o;              o += 512;
  float* shift4  = ws + o;              o += 512;
  float* logits  = ws + o;              o += 64;
  (void)ws_size; (void)in_sizes; (void)n_in; (void)out_size;

  const int npix = B_*HW_;
  const int pixBlocks = (npix + 255)/256;

  k_zero_flag<<<1, 64, 0, stream>>>(flag);
  k_flag<<<2048, 256, 0, stream>>>((const float4*)source, (B_*3*HW_)/4, flag);
  k_detector<<<pixBlocks, 256, 0, stream>>>(source, flag, maskbuf);
  k_box_row<<<pixBlocks, 256, 0, stream>>>(maskbuf, rowsum);
  k_box_col<<<pixBlocks, 256, 0, stream>>>(rowsum, maskbuf);   // window overwrites mask
  k_topk<<<B_, 1024, 0, stream>>>(maskbuf, rand_sel, coords);
  k_patch<<<(NPATCH*3*64*64 + 255)/256, 256, 0, stream>>>(pred, coords, patches);

  k_conv1<<<(NPATCH*64*32 + 255)/256, 256, 0, stream>>>(patches, w1, b1, a1);

  k_conv_s2<64, 128, 32, false><<<(NPATCH*64*16 + 255)/256, 256, 0, stream>>>(
      a1, w2, b2, nullptr, nullptr, z2);
  k_bnstats<128, 256><<<128, 256, 0, stream>>>(z2, g2, be2, scale2, shift2);

  k_conv_s2<128, 256, 16, true><<<(NPATCH*128*8 + 255)/256, 256, 0, stream>>>(
      z2, w3, b3, scale2, shift2, z3);
  k_bnstats<256, 64><<<256, 256, 0, stream>>>(z3, g3, be3, scale3, shift3);

  k_conv_s2<256, 512, 8, true><<<(NPATCH*256*4 + 255)/256, 256, 0, stream>>>(
      z3, w4, b4, scale3, shift3, z4);
  k_bnstats<512, 16><<<512, 256, 0, stream>>>(z4, g4, be4, scale4, shift4);

  k_conv5<<<NPATCH, 256, 0, stream>>>(z4, scale4, shift4, w5, b5, logits);
  k_loss<<<1, 64, 0, stream>>>(logits, (float*)d_out);
}